// Round 6
// baseline (1222.949 us; speedup 1.0000x reference)
//
#include <hip/hip_runtime.h>
#include <hip/hip_fp16.h>
#include <math.h>

#define N_NODES 100000
#define N_EDGES 1600000
#define D_FEAT  64

#define NBC     196    // coarse buckets (dst>>9), 512 nodes each
#define NPB_C   512
#define NFINE   3125   // fine buckets (dst>>5), 32 nodes each; 3125*32 = 100000 exact
#define F1_WGS  512
#define CHUNK_E ((N_EDGES + F1_WGS - 1) / F1_WGS)  // 3125 edges per WG
#define REF_CAP 10240  // refine LDS stage (40 KB); bucket ecnt ~ Poisson(8163)

// ---- helpers ------------------------------------------------------------

__device__ __forceinline__ void unp8(uint4 u, float* a) {
    { __half2 h = *(__half2*)&u.x; float2 f = __half22float2(h); a[0]=f.x; a[1]=f.y; }
    { __half2 h = *(__half2*)&u.y; float2 f = __half22float2(h); a[2]=f.x; a[3]=f.y; }
    { __half2 h = *(__half2*)&u.z; float2 f = __half22float2(h); a[4]=f.x; a[5]=f.y; }
    { __half2 h = *(__half2*)&u.w; float2 f = __half22float2(h); a[6]=f.x; a[7]=f.y; }
}

__device__ __forceinline__ uint4 pack8(const float* v) {
    __half2 h0 = __floats2half2_rn(v[0], v[1]);
    __half2 h1 = __floats2half2_rn(v[2], v[3]);
    __half2 h2 = __floats2half2_rn(v[4], v[5]);
    __half2 h3 = __floats2half2_rn(v[6], v[7]);
    uint4 st;
    st.x = *(unsigned*)&h0; st.y = *(unsigned*)&h1;
    st.z = *(unsigned*)&h2; st.w = *(unsigned*)&h3;
    return st;
}

// ---- cast f32 rows -> row-major fp16 table ------------------------------

__global__ void cast_feat(const float* __restrict__ in,
                          __half* __restrict__ out) {
    int i = blockIdx.x * blockDim.x + threadIdx.x;   // one per 4 elems
    if (i >= (N_NODES * D_FEAT) / 4) return;
    float4 v = ((const float4*)in)[i];
    __half2 h0 = __floats2half2_rn(v.x, v.y);
    __half2 h1 = __floats2half2_rn(v.z, v.w);
    uint2 st;
    st.x = *(unsigned*)&h0;
    st.y = *(unsigned*)&h1;
    ((uint2*)out)[i] = st;
}

// ---- coarse bucket build (proven from rounds 3-4) -----------------------

__global__ void bucket_hist(const int* __restrict__ dst,
                            int* __restrict__ percnt) {
    __shared__ int cnt[NBC];
    for (int i = threadIdx.x; i < NBC; i += blockDim.x) cnt[i] = 0;
    __syncthreads();
    int e0 = blockIdx.x * CHUNK_E;
    int e1 = min(e0 + CHUNK_E, N_EDGES);
    for (int e = e0 + threadIdx.x; e < e1; e += blockDim.x)
        atomicAdd(&cnt[dst[e] >> 9], 1);
    __syncthreads();
    for (int i = threadIdx.x; i < NBC; i += blockDim.x)
        percnt[i * F1_WGS + blockIdx.x] = cnt[i];
}

__global__ void bucket_colscan(int* __restrict__ percnt,
                               int* __restrict__ bhist) {
    __shared__ int tmp[F1_WGS];
    int b = blockIdx.x;
    int v = percnt[b * F1_WGS + threadIdx.x];
    tmp[threadIdx.x] = v;
    __syncthreads();
    for (int o = 1; o < F1_WGS; o <<= 1) {
        int t = (threadIdx.x >= o) ? tmp[threadIdx.x - o] : 0;
        __syncthreads();
        tmp[threadIdx.x] += t;
        __syncthreads();
    }
    percnt[b * F1_WGS + threadIdx.x] = tmp[threadIdx.x] - v;  // exclusive
    if (threadIdx.x == F1_WGS - 1) bhist[b] = tmp[F1_WGS - 1];
}

__global__ void bucket_scan(const int* __restrict__ bhist,
                            int* __restrict__ bbase) {
    __shared__ int tmp[256];
    int i = threadIdx.x;
    int v = (i < NBC) ? bhist[i] : 0;
    tmp[i] = v;
    __syncthreads();
    for (int o = 1; o < 256; o <<= 1) {
        int t = (i >= o) ? tmp[i - o] : 0;
        __syncthreads();
        tmp[i] += t;
        __syncthreads();
    }
    if (i < NBC) bbase[i] = tmp[i] - v;
    if (i == 0) bbase[NBC] = N_EDGES;
}

// Scatter edges into coarse-bucket-contiguous tmp1, packed (src<<9)|(dst&511).
__global__ void bucketize(const int* __restrict__ src,
                          const int* __restrict__ dst,
                          const int* __restrict__ bbase,
                          const int* __restrict__ percnt,
                          unsigned int* __restrict__ tmp1) {
    __shared__ int base[NBC];
    __shared__ int cur[NBC];
    int wg = blockIdx.x;
    for (int i = threadIdx.x; i < NBC; i += blockDim.x) {
        base[i] = bbase[i] + percnt[i * F1_WGS + wg];
        cur[i] = 0;
    }
    __syncthreads();
    int e0 = wg * CHUNK_E;
    int e1 = min(e0 + CHUNK_E, N_EDGES);
    for (int e = e0 + threadIdx.x; e < e1; e += blockDim.x) {
        int d = dst[e];
        int b = d >> 9;
        int r = atomicAdd(&cur[b], 1);
        tmp1[base[b] + r] = ((unsigned)src[e] << 9) | (unsigned)(d & 511);
    }
}

// ---- refine: coarse(512) -> fine(32-node) buckets, LDS-staged -----------
// One WG per coarse bucket. Writes fine-contiguous tmp2 (runs ~510 edges)
// packed (src<<5)|(dst&31), and fbase[] fine-bucket offsets.

__global__ __launch_bounds__(512) void refine_kernel(
        const unsigned int* __restrict__ tmp1,
        const int* __restrict__ bbase,
        unsigned int* __restrict__ tmp2,
        int* __restrict__ fbase) {
    __shared__ unsigned int stage[REF_CAP];
    __shared__ int fcnt[16], foff[16], fcur[16];
    int b = blockIdx.x, t = threadIdx.x;
    int e0 = bbase[b], e1 = bbase[b + 1], ecnt = e1 - e0;
    if (t < 16) fcnt[t] = 0;
    __syncthreads();
    bool fit = (ecnt <= REF_CAP);
    for (int i = t; i < ecnt; i += 512) {
        unsigned u = tmp1[e0 + i];
        if (fit) stage[i] = u;
        atomicAdd(&fcnt[(u >> 5) & 15], 1);   // fine = (dst&511)>>5
    }
    __syncthreads();
    if (t == 0) {
        int run = e0;
        #pragma unroll
        for (int j = 0; j < 16; j++) { foff[j] = run; fcur[j] = 0; run += fcnt[j]; }
    }
    __syncthreads();
    if (t < 16) fbase[b * 16 + t] = foff[t];
    if (b == NBC - 1 && t == 0) fbase[NBC * 16] = N_EDGES;
    for (int i = t; i < ecnt; i += 512) {
        unsigned u = fit ? stage[i] : tmp1[e0 + i];
        int j = (u >> 5) & 15;
        int r = atomicAdd(&fcur[j], 1);
        tmp2[foff[j] + r] = ((u >> 9) << 5) | (u & 31);
    }
}

// ---- aggregation: one WG per fine bucket, fp32 accumulators in LDS ------
// 256 threads = 8 edge-slots x 32 lanes. Per edge: broadcast packed edge,
// 32 lanes load 4 B (half2) of the random 128 B row, LDS-atomicAdd fp32.

__global__ __launch_bounds__(256) void scatter_agg(
        const __half* __restrict__ tbl,
        const unsigned int* __restrict__ edges,
        const int* __restrict__ fbase,
        __half* __restrict__ out_tbl) {
    __shared__ float acc[32 * 64];
    __shared__ int degc[32];
    int f = blockIdx.x, t = threadIdx.x;
    for (int i = t; i < 32 * 64; i += 256) acc[i] = 0.f;
    if (t < 32) degc[t] = 0;
    __syncthreads();
    int e1 = fbase[f + 1];
    int slot = t >> 5, l = t & 31;
    for (int e = fbase[f] + slot; e < e1; e += 8) {
        unsigned u = edges[e];
        int dl = u & 31;
        int s  = (int)(u >> 5);
        unsigned w = *(const unsigned*)(tbl + ((size_t)s << 6) + (l << 1));
        __half2 h = *(__half2*)&w;
        float2 fv = __half22float2(h);
        atomicAdd(&acc[dl * 64 + l * 2],     fv.x);
        atomicAdd(&acc[dl * 64 + l * 2 + 1], fv.y);
        if (l == 0) atomicAdd(&degc[dl], 1);
    }
    __syncthreads();
    int n = t >> 3, fo = (t & 7) * 8;
    int node = f * 32 + n;                    // 3125*32 = 100000 exact
    int dg = degc[n];
    float inv = (dg > 0) ? 1.0f / (float)dg : 0.f;
    float r[8];
    #pragma unroll
    for (int k = 0; k < 8; k++) r[k] = acc[n * 64 + fo + k] * inv;
    *(uint4*)(out_tbl + ((size_t)node << 6) + fo) = pack8(r);
}

// Round 2 + fused cosine blend epilogue (x2 never materialized).
__global__ __launch_bounds__(256) void scatter_agg_fin(
        const __half* __restrict__ x1,
        const unsigned int* __restrict__ edges,
        const int* __restrict__ fbase,
        float* __restrict__ out) {
    __shared__ float acc[32 * 64];
    __shared__ int degc[32];
    int f = blockIdx.x, t = threadIdx.x;
    for (int i = t; i < 32 * 64; i += 256) acc[i] = 0.f;
    if (t < 32) degc[t] = 0;
    __syncthreads();
    int e1 = fbase[f + 1];
    int slot = t >> 5, l = t & 31;
    for (int e = fbase[f] + slot; e < e1; e += 8) {
        unsigned u = edges[e];
        int dl = u & 31;
        int s  = (int)(u >> 5);
        unsigned w = *(const unsigned*)(x1 + ((size_t)s << 6) + (l << 1));
        __half2 h = *(__half2*)&w;
        float2 fv = __half22float2(h);
        atomicAdd(&acc[dl * 64 + l * 2],     fv.x);
        atomicAdd(&acc[dl * 64 + l * 2 + 1], fv.y);
        if (l == 0) atomicAdd(&degc[dl], 1);
    }
    __syncthreads();
    int n = t >> 3, fo = (t & 7) * 8;
    int node = f * 32 + n;
    int dg = degc[n];
    float inv = (dg > 0) ? 1.0f / (float)dg : 0.f;
    float b[8];
    #pragma unroll
    for (int k = 0; k < 8; k++) b[k] = acc[n * 64 + fo + k] * inv;
    float a[8];
    uint4 ua = *(const uint4*)(x1 + ((size_t)node << 6) + fo);
    unp8(ua, a);
    float dot = 0.f, nn1 = 0.f, nn2 = 0.f;
    #pragma unroll
    for (int k = 0; k < 8; k++) {
        dot += a[k] * b[k];
        nn1 += a[k] * a[k];
        nn2 += b[k] * b[k];
    }
    #pragma unroll
    for (int m = 1; m < 8; m <<= 1) {   // 8 threads per node, same wave
        dot += __shfl_xor(dot, m);
        nn1 += __shfl_xor(nn1, m);
        nn2 += __shfl_xor(nn2, m);
    }
    float w = dot / fmaxf(sqrtf(nn1) * sqrtf(nn2), 1e-8f);
    float omw = 1.0f - w;
    float4 r0, r1;
    r0.x = w*b[0] + omw*a[0]; r0.y = w*b[1] + omw*a[1];
    r0.z = w*b[2] + omw*a[2]; r0.w = w*b[3] + omw*a[3];
    r1.x = w*b[4] + omw*a[4]; r1.y = w*b[5] + omw*a[5];
    r1.z = w*b[6] + omw*a[6]; r1.w = w*b[7] + omw*a[7];
    float* po = out + ((size_t)node << 6) + fo;
    *(float4*)po = r0;
    *(float4*)(po + 4) = r1;
}

// ---- launch -------------------------------------------------------------

extern "C" void kernel_launch(void* const* d_in, const int* in_sizes, int n_in,
                              void* d_out, int out_size, void* d_ws, size_t ws_size,
                              hipStream_t stream) {
    const float* feat = (const float*)d_in[0];
    const int*   eidx = (const int*)d_in[1];
    const int*   src  = eidx;
    const int*   dst  = eidx + N_EDGES;

    __half*       feat_h = (__half*)d_ws;                           // 12.8 MB
    __half*       x1_h   = feat_h + (size_t)N_NODES * D_FEAT;       // 12.8 MB
    unsigned int* tmp1   = (unsigned int*)(x1_h + (size_t)N_NODES * D_FEAT); // 6.4 MB
    unsigned int* tmp2   = tmp1 + N_EDGES;                          // 6.4 MB
    int*          percnt = (int*)(tmp2 + N_EDGES);                  // NBC*F1_WGS
    int*          bhist  = percnt + NBC * F1_WGS;                   // NBC
    int*          bbase  = bhist + NBC;                             // NBC+1
    int*          fbase  = bbase + (NBC + 1);                       // NBC*16+1
    float*        out    = (float*)d_out;

    const int BLK = 256;
    int castn = (N_NODES * D_FEAT) / 4;
    cast_feat<<<(castn + BLK - 1) / BLK, BLK, 0, stream>>>(feat, feat_h);

    bucket_hist   <<<F1_WGS, 256, 0, stream>>>(dst, percnt);
    bucket_colscan<<<NBC, F1_WGS, 0, stream>>>(percnt, bhist);
    bucket_scan   <<<1, 256, 0, stream>>>(bhist, bbase);
    bucketize     <<<F1_WGS, 256, 0, stream>>>(src, dst, bbase, percnt, tmp1);
    refine_kernel <<<NBC, 512, 0, stream>>>(tmp1, bbase, tmp2, fbase);

    scatter_agg    <<<NFINE, 256, 0, stream>>>(feat_h, tmp2, fbase, x1_h);
    scatter_agg_fin<<<NFINE, 256, 0, stream>>>(x1_h, tmp2, fbase, out);
}

// Round 7
// 204.865 us; speedup vs baseline: 5.9695x; 5.9695x over previous
//
#include <hip/hip_runtime.h>
#include <hip/hip_fp16.h>
#include <math.h>

#define N_NODES 100000
#define N_EDGES 1600000
#define D_FEAT  64

#define NPB     512                                // nodes per bucket (dst>>9)
#define NBC     ((N_NODES + NPB - 1) / NPB)        // 196 buckets
#define F1_WGS  512                                // chunking WGs for hist/bucketize
#define NV4     (N_EDGES / 4)                      // 400000 int4 edge groups
#define CHUNK_V ((NV4 + F1_WGS - 1) / F1_WGS)      // 782 int4s per WG
#define STAGE_CAP 16384                            // bucket_csr LDS staging (64 KB)

// ---- helpers ------------------------------------------------------------

__device__ __forceinline__ uint4 pack8(const float* v) {
    __half2 h0 = __floats2half2_rn(v[0], v[1]);
    __half2 h1 = __floats2half2_rn(v[2], v[3]);
    __half2 h2 = __floats2half2_rn(v[4], v[5]);
    __half2 h3 = __floats2half2_rn(v[6], v[7]);
    uint4 st;
    st.x = *(unsigned*)&h0; st.y = *(unsigned*)&h1;
    st.z = *(unsigned*)&h2; st.w = *(unsigned*)&h3;
    return st;
}

__device__ __forceinline__ void unp8(uint4 u, float* a) {
    { __half2 h = *(__half2*)&u.x; float2 f = __half22float2(h); a[0]=f.x; a[1]=f.y; }
    { __half2 h = *(__half2*)&u.y; float2 f = __half22float2(h); a[2]=f.x; a[3]=f.y; }
    { __half2 h = *(__half2*)&u.z; float2 f = __half22float2(h); a[4]=f.x; a[5]=f.y; }
    { __half2 h = *(__half2*)&u.w; float2 f = __half22float2(h); a[6]=f.x; a[7]=f.y; }
}

// wave-scan based block exclusive scan over 512 ints (3 barriers total,
// caller provides the post-store barrier). Returns exclusive prefix of v.
__device__ __forceinline__ int block_excl_scan_512(int v, int t, int* wsum) {
    int lane = t & 63, wv = t >> 6;
    int incl = v;
    #pragma unroll
    for (int m = 1; m < 64; m <<= 1) {
        int o = __shfl_up(incl, m);
        if (lane >= m) incl += o;
    }
    if (lane == 63) wsum[wv] = incl;
    __syncthreads();
    int prefix = 0;
    #pragma unroll
    for (int j = 0; j < 8; j++)
        if (j < wv) prefix += wsum[j];
    return prefix + incl - v;
}

// ---- cast f32 rows -> row-major fp16 table ------------------------------

__global__ void cast_feat(const float* __restrict__ in,
                          __half* __restrict__ out) {
    int i = blockIdx.x * blockDim.x + threadIdx.x;   // one per 4 elems
    if (i >= (N_NODES * D_FEAT) / 4) return;
    float4 v = ((const float4*)in)[i];
    __half2 h0 = __floats2half2_rn(v.x, v.y);
    __half2 h1 = __floats2half2_rn(v.z, v.w);
    uint2 st;
    st.x = *(unsigned*)&h0;
    st.y = *(unsigned*)&h1;
    ((uint2*)out)[i] = st;
}

// ---- CSR build ----------------------------------------------------------

__global__ void bucket_hist(const int4* __restrict__ dst4,
                            int* __restrict__ percnt) {
    __shared__ int cnt[NBC];
    for (int i = threadIdx.x; i < NBC; i += blockDim.x) cnt[i] = 0;
    __syncthreads();
    int i0 = blockIdx.x * CHUNK_V;
    int i1 = min(i0 + CHUNK_V, NV4);
    for (int i = i0 + threadIdx.x; i < i1; i += blockDim.x) {
        int4 d = dst4[i];
        atomicAdd(&cnt[d.x >> 9], 1);
        atomicAdd(&cnt[d.y >> 9], 1);
        atomicAdd(&cnt[d.z >> 9], 1);
        atomicAdd(&cnt[d.w >> 9], 1);
    }
    __syncthreads();
    for (int i = threadIdx.x; i < NBC; i += blockDim.x)
        percnt[i * F1_WGS + blockIdx.x] = cnt[i];
}

__global__ __launch_bounds__(F1_WGS) void bucket_colscan(
        int* __restrict__ percnt, int* __restrict__ bhist) {
    __shared__ int wsum[8];
    int b = blockIdx.x, t = threadIdx.x;
    int v = percnt[b * F1_WGS + t];
    int excl = block_excl_scan_512(v, t, wsum);
    percnt[b * F1_WGS + t] = excl;
    if (t == F1_WGS - 1) bhist[b] = excl + v;
}

__global__ void bucket_scan(const int* __restrict__ bhist,
                            int* __restrict__ bbase) {
    __shared__ int tmp[256];
    int i = threadIdx.x;
    int v = (i < NBC) ? bhist[i] : 0;
    tmp[i] = v;
    __syncthreads();
    for (int o = 1; o < 256; o <<= 1) {
        int t = (i >= o) ? tmp[i - o] : 0;
        __syncthreads();
        tmp[i] += t;
        __syncthreads();
    }
    if (i < NBC) bbase[i] = tmp[i] - v;
    if (i == 0) bbase[NBC] = N_EDGES;
}

// Scatter edges into coarse-bucket-contiguous tmp1, packed (src<<9)|(dst&511).
__global__ void bucketize(const int4* __restrict__ src4,
                          const int4* __restrict__ dst4,
                          const int* __restrict__ bbase,
                          const int* __restrict__ percnt,
                          unsigned int* __restrict__ tmp1) {
    __shared__ int base[NBC];
    __shared__ int cur[NBC];
    int wg = blockIdx.x;
    for (int i = threadIdx.x; i < NBC; i += blockDim.x) {
        base[i] = bbase[i] + percnt[i * F1_WGS + wg];
        cur[i] = 0;
    }
    __syncthreads();
    int i0 = wg * CHUNK_V;
    int i1 = min(i0 + CHUNK_V, NV4);
    for (int i = i0 + threadIdx.x; i < i1; i += blockDim.x) {
        int4 d = dst4[i];
        int4 s = src4[i];
        {
            int b = d.x >> 9; int r = atomicAdd(&cur[b], 1);
            tmp1[base[b] + r] = ((unsigned)s.x << 9) | (unsigned)(d.x & 511);
        }
        {
            int b = d.y >> 9; int r = atomicAdd(&cur[b], 1);
            tmp1[base[b] + r] = ((unsigned)s.y << 9) | (unsigned)(d.y & 511);
        }
        {
            int b = d.z >> 9; int r = atomicAdd(&cur[b], 1);
            tmp1[base[b] + r] = ((unsigned)s.z << 9) | (unsigned)(d.z & 511);
        }
        {
            int b = d.w >> 9; int r = atomicAdd(&cur[b], 1);
            tmp1[base[b] + r] = ((unsigned)s.w << 9) | (unsigned)(d.w & 511);
        }
    }
}

// One WG per bucket: LDS node histogram + wave-scan -> offsets (coalesced),
// then LDS-stage within-bucket counting sort -> csr_src flushed coalesced.
__global__ __launch_bounds__(NPB) void bucket_csr(
        const unsigned int* __restrict__ tmp1,
        const int* __restrict__ bbase,
        int* __restrict__ offsets,
        int* __restrict__ csr_src) {
    __shared__ int cnt[NPB];
    __shared__ int off[NPB];
    __shared__ int wsum[8];
    __shared__ int stage[STAGE_CAP];
    int b = blockIdx.x, t = threadIdx.x;
    int ebase = bbase[b];
    int ecnt  = bbase[b + 1] - ebase;
    int node0 = b * NPB;

    cnt[t] = 0;
    __syncthreads();
    for (int i = t; i < ecnt; i += NPB)
        atomicAdd(&cnt[tmp1[ebase + i] & 511], 1);
    __syncthreads();

    int v = cnt[t];
    int excl = block_excl_scan_512(v, t, wsum);   // 1 barrier inside
    off[t] = excl;
    cnt[t] = 0;  // reuse as cursor
    if (node0 + t < N_NODES) offsets[node0 + t] = ebase + excl;
    if (b == NBC - 1 && t == 0) offsets[N_NODES] = N_EDGES;
    __syncthreads();

    if (ecnt <= STAGE_CAP) {
        for (int i = t; i < ecnt; i += NPB) {
            unsigned u = tmp1[ebase + i];
            int d = (int)(u & 511);
            int r = atomicAdd(&cnt[d], 1);
            stage[off[d] + r] = (int)(u >> 9);
        }
        __syncthreads();
        for (int i = t; i < ecnt; i += NPB)
            csr_src[ebase + i] = stage[i];
    } else {
        for (int i = t; i < ecnt; i += NPB) {
            unsigned u = tmp1[ebase + i];
            int d = (int)(u & 511);
            int r = atomicAdd(&cnt[d], 1);
            csr_src[ebase + off[d] + r] = (int)(u >> 9);
        }
    }
}

// ---- Gather passes (fp16 rows, packed-fp16 accumulation) ----------------
// One wave per node: 8 groups x 8 edges in flight; 8 lanes x 16B per row.

__global__ void gather1_kernel(const __half* __restrict__ feat_h,
                               const int* __restrict__ offsets,
                               const int* __restrict__ csr,
                               __half* __restrict__ x1_h) {
    int node = blockIdx.x * (blockDim.x >> 6) + (threadIdx.x >> 6);
    if (node >= N_NODES) return;
    int lane = threadIdx.x & 63;
    int g = lane >> 3;
    int fid = (lane & 7) * 8;

    int base = offsets[node];
    int deg = offsets[node + 1] - base;

    __half2 h0 = __float2half2_rn(0.f), h1 = h0, h2 = h0, h3 = h0;
    for (int j = g; j < deg; j += 8) {
        int s = csr[base + j];
        uint4 u = *(const uint4*)(feat_h + ((size_t)s << 6) + fid);
        h0 = __hadd2(h0, *(__half2*)&u.x);
        h1 = __hadd2(h1, *(__half2*)&u.y);
        h2 = __hadd2(h2, *(__half2*)&u.z);
        h3 = __hadd2(h3, *(__half2*)&u.w);
    }
    float acc[8];
    { float2 f = __half22float2(h0); acc[0]=f.x; acc[1]=f.y; }
    { float2 f = __half22float2(h1); acc[2]=f.x; acc[3]=f.y; }
    { float2 f = __half22float2(h2); acc[4]=f.x; acc[5]=f.y; }
    { float2 f = __half22float2(h3); acc[6]=f.x; acc[7]=f.y; }
    #pragma unroll
    for (int m = 8; m < 64; m <<= 1)
        #pragma unroll
        for (int t = 0; t < 8; t++)
            acc[t] += __shfl_xor(acc[t], m);

    if (lane < 8) {
        float inv = (deg > 0) ? 1.0f / (float)deg : 0.0f;
        float r[8];
        #pragma unroll
        for (int t = 0; t < 8; t++) r[t] = acc[t] * inv;
        *(uint4*)(x1_h + ((size_t)node << 6) + fid) = pack8(r);
    }
}

__global__ void gather2_finalize_kernel(const __half* __restrict__ x1_h,
                                        const int* __restrict__ offsets,
                                        const int* __restrict__ csr,
                                        float* __restrict__ out) {
    int node = blockIdx.x * (blockDim.x >> 6) + (threadIdx.x >> 6);
    if (node >= N_NODES) return;
    int lane = threadIdx.x & 63;
    int g = lane >> 3;
    int fid = (lane & 7) * 8;

    int base = offsets[node];
    int deg = offsets[node + 1] - base;

    __half2 h0 = __float2half2_rn(0.f), h1 = h0, h2 = h0, h3 = h0;
    for (int j = g; j < deg; j += 8) {
        int s = csr[base + j];
        uint4 u = *(const uint4*)(x1_h + ((size_t)s << 6) + fid);
        h0 = __hadd2(h0, *(__half2*)&u.x);
        h1 = __hadd2(h1, *(__half2*)&u.y);
        h2 = __hadd2(h2, *(__half2*)&u.z);
        h3 = __hadd2(h3, *(__half2*)&u.w);
    }
    float acc[8];
    { float2 f = __half22float2(h0); acc[0]=f.x; acc[1]=f.y; }
    { float2 f = __half22float2(h1); acc[2]=f.x; acc[3]=f.y; }
    { float2 f = __half22float2(h2); acc[4]=f.x; acc[5]=f.y; }
    { float2 f = __half22float2(h3); acc[6]=f.x; acc[7]=f.y; }
    #pragma unroll
    for (int m = 8; m < 64; m <<= 1)
        #pragma unroll
        for (int t = 0; t < 8; t++)
            acc[t] += __shfl_xor(acc[t], m);

    float inv = (deg > 0) ? 1.0f / (float)deg : 0.0f;
    float b[8], a[8];
    #pragma unroll
    for (int t = 0; t < 8; t++) b[t] = acc[t] * inv;

    uint4 ua = *(const uint4*)(x1_h + ((size_t)node << 6) + fid);
    unp8(ua, a);

    float dot = 0.f, nn1 = 0.f, nn2 = 0.f;
    #pragma unroll
    for (int t = 0; t < 8; t++) {
        dot += a[t] * b[t];
        nn1 += a[t] * a[t];
        nn2 += b[t] * b[t];
    }
    #pragma unroll
    for (int m = 1; m < 64; m <<= 1) {
        dot += __shfl_xor(dot, m);
        nn1 += __shfl_xor(nn1, m);
        nn2 += __shfl_xor(nn2, m);
    }
    dot *= 0.125f; nn1 *= 0.125f; nn2 *= 0.125f;  // 8 groups duplicate

    float w = dot / fmaxf(sqrtf(nn1) * sqrtf(nn2), 1e-8f);
    if (lane < 8) {
        float omw = 1.0f - w;
        float4 r0, r1;
        r0.x = w*b[0] + omw*a[0]; r0.y = w*b[1] + omw*a[1];
        r0.z = w*b[2] + omw*a[2]; r0.w = w*b[3] + omw*a[3];
        r1.x = w*b[4] + omw*a[4]; r1.y = w*b[5] + omw*a[5];
        r1.z = w*b[6] + omw*a[6]; r1.w = w*b[7] + omw*a[7];
        float* po = out + ((size_t)node << 6) + fid;
        *(float4*)po = r0;
        *(float4*)(po + 4) = r1;
    }
}

// ---- launch -------------------------------------------------------------

extern "C" void kernel_launch(void* const* d_in, const int* in_sizes, int n_in,
                              void* d_out, int out_size, void* d_ws, size_t ws_size,
                              hipStream_t stream) {
    const float* feat = (const float*)d_in[0];
    const int*   eidx = (const int*)d_in[1];
    const int4*  src4 = (const int4*)eidx;
    const int4*  dst4 = (const int4*)(eidx + N_EDGES);

    __half*       feat_h  = (__half*)d_ws;                          // 12.8 MB
    __half*       x1_h    = feat_h + (size_t)N_NODES * D_FEAT;      // 12.8 MB
    unsigned int* tmp1    = (unsigned int*)(x1_h + (size_t)N_NODES * D_FEAT); // 6.4 MB
    int*          csr_src = (int*)(tmp1 + N_EDGES);                 // 6.4 MB
    int*          offsets = csr_src + N_EDGES;                      // 100001
    int*          percnt  = offsets + (N_NODES + 1);                // NBC*F1_WGS
    int*          bhist   = percnt + NBC * F1_WGS;                  // NBC
    int*          bbase   = bhist + NBC;                            // NBC+1
    float*        out     = (float*)d_out;

    const int BLK = 256;
    int castn = (N_NODES * D_FEAT) / 4;
    cast_feat<<<(castn + BLK - 1) / BLK, BLK, 0, stream>>>(feat, feat_h);

    bucket_hist   <<<F1_WGS, 256, 0, stream>>>(dst4, percnt);
    bucket_colscan<<<NBC, F1_WGS, 0, stream>>>(percnt, bhist);
    bucket_scan   <<<1, 256, 0, stream>>>(bhist, bbase);
    bucketize     <<<F1_WGS, 256, 0, stream>>>(src4, dst4, bbase, percnt, tmp1);
    bucket_csr    <<<NBC, NPB, 0, stream>>>(tmp1, bbase, offsets, csr_src);

    int nodes_per_block = BLK / 64;  // 4
    int nblocks = (N_NODES + nodes_per_block - 1) / nodes_per_block;
    gather1_kernel<<<nblocks, BLK, 0, stream>>>(feat_h, offsets, csr_src, x1_h);
    gather2_finalize_kernel<<<nblocks, BLK, 0, stream>>>(x1_h, offsets, csr_src, out);
}

// Round 9
// 200.923 us; speedup vs baseline: 6.0867x; 1.0196x over previous
//
#include <hip/hip_runtime.h>
#include <hip/hip_fp16.h>
#include <math.h>

#define N_NODES 100000
#define N_EDGES 1600000
#define D_FEAT  64

#define NPB     512                                // nodes per bucket (dst>>9)
#define NBC     ((N_NODES + NPB - 1) / NPB)        // 196 buckets
#define F1_WGS  512                                // chunking WGs for hist/bucketize
#define NV4     (N_EDGES / 4)                      // 400000 int4 edge groups
#define CHUNK_V ((NV4 + F1_WGS - 1) / F1_WGS)      // 782 int4s per WG
#define STAGE_CAP 16384                            // bucket_csr LDS staging (64 KB)
#define CASTN   ((N_NODES * D_FEAT) / 4)           // 1.6M float4 groups
#define CAST_BLOCKS ((CASTN + 255) / 256)          // 6250

// ---- helpers ------------------------------------------------------------

__device__ __forceinline__ uint4 pack8(const float* v) {
    __half2 h0 = __floats2half2_rn(v[0], v[1]);
    __half2 h1 = __floats2half2_rn(v[2], v[3]);
    __half2 h2 = __floats2half2_rn(v[4], v[5]);
    __half2 h3 = __floats2half2_rn(v[6], v[7]);
    uint4 st;
    st.x = *(unsigned*)&h0; st.y = *(unsigned*)&h1;
    st.z = *(unsigned*)&h2; st.w = *(unsigned*)&h3;
    return st;
}

__device__ __forceinline__ void unp8(uint4 u, float* a) {
    { __half2 h = *(__half2*)&u.x; float2 f = __half22float2(h); a[0]=f.x; a[1]=f.y; }
    { __half2 h = *(__half2*)&u.y; float2 f = __half22float2(h); a[2]=f.x; a[3]=f.y; }
    { __half2 h = *(__half2*)&u.z; float2 f = __half22float2(h); a[4]=f.x; a[5]=f.y; }
    { __half2 h = *(__half2*)&u.w; float2 f = __half22float2(h); a[6]=f.x; a[7]=f.y; }
}

// wave-scan based block exclusive scan over 512 ints.
__device__ __forceinline__ int block_excl_scan_512(int v, int t, int* wsum) {
    int lane = t & 63, wv = t >> 6;
    int incl = v;
    #pragma unroll
    for (int m = 1; m < 64; m <<= 1) {
        int o = __shfl_up(incl, m);
        if (lane >= m) incl += o;
    }
    if (lane == 63) wsum[wv] = incl;
    __syncthreads();
    int prefix = 0;
    #pragma unroll
    for (int j = 0; j < 8; j++)
        if (j < wv) prefix += wsum[j];
    return prefix + incl - v;
}

// ---- fused cast + coarse histogram --------------------------------------
// blocks [0, F1_WGS): histogram chunk; blocks [F1_WGS, ...): cast.

__global__ void cast_and_hist(const float* __restrict__ feat,
                              __half* __restrict__ feat_h,
                              const int4* __restrict__ dst4,
                              int* __restrict__ percnt) {
    if (blockIdx.x >= F1_WGS) {
        int i = (blockIdx.x - F1_WGS) * 256 + threadIdx.x;
        if (i < CASTN) {
            float4 v = ((const float4*)feat)[i];
            __half2 h0 = __floats2half2_rn(v.x, v.y);
            __half2 h1 = __floats2half2_rn(v.z, v.w);
            uint2 st;
            st.x = *(unsigned*)&h0;
            st.y = *(unsigned*)&h1;
            ((uint2*)feat_h)[i] = st;
        }
        return;
    }
    __shared__ int cnt[NBC];
    for (int i = threadIdx.x; i < NBC; i += blockDim.x) cnt[i] = 0;
    __syncthreads();
    int i0 = blockIdx.x * CHUNK_V;
    int i1 = min(i0 + CHUNK_V, NV4);
    for (int i = i0 + threadIdx.x; i < i1; i += blockDim.x) {
        int4 d = dst4[i];
        atomicAdd(&cnt[d.x >> 9], 1);
        atomicAdd(&cnt[d.y >> 9], 1);
        atomicAdd(&cnt[d.z >> 9], 1);
        atomicAdd(&cnt[d.w >> 9], 1);
    }
    __syncthreads();
    for (int i = threadIdx.x; i < NBC; i += blockDim.x)
        percnt[i * F1_WGS + blockIdx.x] = cnt[i];
}

// ---- CSR build ----------------------------------------------------------

__global__ __launch_bounds__(F1_WGS) void bucket_colscan(
        int* __restrict__ percnt, int* __restrict__ bhist) {
    __shared__ int wsum[8];
    int b = blockIdx.x, t = threadIdx.x;
    int v = percnt[b * F1_WGS + t];
    int excl = block_excl_scan_512(v, t, wsum);
    percnt[b * F1_WGS + t] = excl;
    if (t == F1_WGS - 1) bhist[b] = excl + v;
}

__global__ void bucket_scan(const int* __restrict__ bhist,
                            int* __restrict__ bbase) {
    __shared__ int tmp[256];
    int i = threadIdx.x;
    int v = (i < NBC) ? bhist[i] : 0;
    tmp[i] = v;
    __syncthreads();
    for (int o = 1; o < 256; o <<= 1) {
        int t = (i >= o) ? tmp[i - o] : 0;
        __syncthreads();
        tmp[i] += t;
        __syncthreads();
    }
    if (i < NBC) bbase[i] = tmp[i] - v;
    if (i == 0) bbase[NBC] = N_EDGES;
}

__global__ void bucketize(const int4* __restrict__ src4,
                          const int4* __restrict__ dst4,
                          const int* __restrict__ bbase,
                          const int* __restrict__ percnt,
                          unsigned int* __restrict__ tmp1) {
    __shared__ int base[NBC];
    __shared__ int cur[NBC];
    int wg = blockIdx.x;
    for (int i = threadIdx.x; i < NBC; i += blockDim.x) {
        base[i] = bbase[i] + percnt[i * F1_WGS + wg];
        cur[i] = 0;
    }
    __syncthreads();
    int i0 = wg * CHUNK_V;
    int i1 = min(i0 + CHUNK_V, NV4);
    for (int i = i0 + threadIdx.x; i < i1; i += blockDim.x) {
        int4 d = dst4[i];
        int4 s = src4[i];
        {
            int b = d.x >> 9; int r = atomicAdd(&cur[b], 1);
            tmp1[base[b] + r] = ((unsigned)s.x << 9) | (unsigned)(d.x & 511);
        }
        {
            int b = d.y >> 9; int r = atomicAdd(&cur[b], 1);
            tmp1[base[b] + r] = ((unsigned)s.y << 9) | (unsigned)(d.y & 511);
        }
        {
            int b = d.z >> 9; int r = atomicAdd(&cur[b], 1);
            tmp1[base[b] + r] = ((unsigned)s.z << 9) | (unsigned)(d.z & 511);
        }
        {
            int b = d.w >> 9; int r = atomicAdd(&cur[b], 1);
            tmp1[base[b] + r] = ((unsigned)s.w << 9) | (unsigned)(d.w & 511);
        }
    }
}

__global__ __launch_bounds__(NPB) void bucket_csr(
        const unsigned int* __restrict__ tmp1,
        const int* __restrict__ bbase,
        int* __restrict__ offsets,
        int* __restrict__ csr_src) {
    __shared__ int cnt[NPB];
    __shared__ int off[NPB];
    __shared__ int wsum[8];
    __shared__ int stage[STAGE_CAP];
    int b = blockIdx.x, t = threadIdx.x;
    int ebase = bbase[b];
    int ecnt  = bbase[b + 1] - ebase;
    int node0 = b * NPB;

    cnt[t] = 0;
    __syncthreads();
    for (int i = t; i < ecnt; i += NPB)
        atomicAdd(&cnt[tmp1[ebase + i] & 511], 1);
    __syncthreads();

    int v = cnt[t];
    int excl = block_excl_scan_512(v, t, wsum);
    off[t] = excl;
    cnt[t] = 0;  // reuse as cursor
    if (node0 + t < N_NODES) offsets[node0 + t] = ebase + excl;
    if (b == NBC - 1 && t == 0) offsets[N_NODES] = N_EDGES;
    __syncthreads();

    if (ecnt <= STAGE_CAP) {
        for (int i = t; i < ecnt; i += NPB) {
            unsigned u = tmp1[ebase + i];
            int d = (int)(u & 511);
            int r = atomicAdd(&cnt[d], 1);
            stage[off[d] + r] = (int)(u >> 9);
        }
        __syncthreads();
        for (int i = t; i < ecnt; i += NPB)
            csr_src[ebase + i] = stage[i];
    } else {
        for (int i = t; i < ecnt; i += NPB) {
            unsigned u = tmp1[ebase + i];
            int d = (int)(u & 511);
            int r = atomicAdd(&cnt[d], 1);
            csr_src[ebase + off[d] + r] = (int)(u >> 9);
        }
    }
}

// ---- Gather passes (round-7 proven structure; csr staged via LDS) -------
// One wave per node. csr entries preloaded with ONE coalesced wave load
// into LDS (wave-private row; broadcast reads, conflict-free), so row
// loads are not gated by per-iteration csr load latency.

__global__ void gather1_kernel(const __half* __restrict__ feat_h,
                               const int* __restrict__ offsets,
                               const int* __restrict__ csr,
                               __half* __restrict__ x1_h) {
    __shared__ int scsr[4][64];
    int wv = threadIdx.x >> 6;
    int node = blockIdx.x * 4 + wv;
    if (node >= N_NODES) return;
    int lane = threadIdx.x & 63;
    int g = lane >> 3;
    int fid = (lane & 7) * 8;

    int base = offsets[node];
    int deg = offsets[node + 1] - base;

    if (lane < deg) scsr[wv][lane] = csr[base + lane];   // one wave load
    __builtin_amdgcn_wave_barrier();

    __half2 h0 = __float2half2_rn(0.f), h1 = h0, h2 = h0, h3 = h0;
    int dmax = min(deg, 64);
    for (int j = g; j < dmax; j += 8) {
        int s = scsr[wv][j];
        uint4 u = *(const uint4*)(feat_h + ((size_t)s << 6) + fid);
        h0 = __hadd2(h0, *(__half2*)&u.x);
        h1 = __hadd2(h1, *(__half2*)&u.y);
        h2 = __hadd2(h2, *(__half2*)&u.z);
        h3 = __hadd2(h3, *(__half2*)&u.w);
    }
    for (int j = 64 + g; j < deg; j += 8) {              // cold tail
        int s = csr[base + j];
        uint4 u = *(const uint4*)(feat_h + ((size_t)s << 6) + fid);
        h0 = __hadd2(h0, *(__half2*)&u.x);
        h1 = __hadd2(h1, *(__half2*)&u.y);
        h2 = __hadd2(h2, *(__half2*)&u.z);
        h3 = __hadd2(h3, *(__half2*)&u.w);
    }
    float acc[8];
    { float2 f = __half22float2(h0); acc[0]=f.x; acc[1]=f.y; }
    { float2 f = __half22float2(h1); acc[2]=f.x; acc[3]=f.y; }
    { float2 f = __half22float2(h2); acc[4]=f.x; acc[5]=f.y; }
    { float2 f = __half22float2(h3); acc[6]=f.x; acc[7]=f.y; }
    #pragma unroll
    for (int m = 8; m < 64; m <<= 1)
        #pragma unroll
        for (int t = 0; t < 8; t++)
            acc[t] += __shfl_xor(acc[t], m);

    if (lane < 8) {
        float inv = (deg > 0) ? 1.0f / (float)deg : 0.0f;
        float r[8];
        #pragma unroll
        for (int t = 0; t < 8; t++) r[t] = acc[t] * inv;
        *(uint4*)(x1_h + ((size_t)node << 6) + fid) = pack8(r);
    }
}

__global__ void gather2_finalize_kernel(const __half* __restrict__ x1_h,
                                        const int* __restrict__ offsets,
                                        const int* __restrict__ csr,
                                        float* __restrict__ out) {
    __shared__ int scsr[4][64];
    int wv = threadIdx.x >> 6;
    int node = blockIdx.x * 4 + wv;
    if (node >= N_NODES) return;
    int lane = threadIdx.x & 63;
    int g = lane >> 3;
    int fid = (lane & 7) * 8;

    int base = offsets[node];
    int deg = offsets[node + 1] - base;

    if (lane < deg) scsr[wv][lane] = csr[base + lane];
    __builtin_amdgcn_wave_barrier();

    __half2 h0 = __float2half2_rn(0.f), h1 = h0, h2 = h0, h3 = h0;
    int dmax = min(deg, 64);
    for (int j = g; j < dmax; j += 8) {
        int s = scsr[wv][j];
        uint4 u = *(const uint4*)(x1_h + ((size_t)s << 6) + fid);
        h0 = __hadd2(h0, *(__half2*)&u.x);
        h1 = __hadd2(h1, *(__half2*)&u.y);
        h2 = __hadd2(h2, *(__half2*)&u.z);
        h3 = __hadd2(h3, *(__half2*)&u.w);
    }
    for (int j = 64 + g; j < deg; j += 8) {
        int s = csr[base + j];
        uint4 u = *(const uint4*)(x1_h + ((size_t)s << 6) + fid);
        h0 = __hadd2(h0, *(__half2*)&u.x);
        h1 = __hadd2(h1, *(__half2*)&u.y);
        h2 = __hadd2(h2, *(__half2*)&u.z);
        h3 = __hadd2(h3, *(__half2*)&u.w);
    }
    float acc[8];
    { float2 f = __half22float2(h0); acc[0]=f.x; acc[1]=f.y; }
    { float2 f = __half22float2(h1); acc[2]=f.x; acc[3]=f.y; }
    { float2 f = __half22float2(h2); acc[4]=f.x; acc[5]=f.y; }
    { float2 f = __half22float2(h3); acc[6]=f.x; acc[7]=f.y; }
    #pragma unroll
    for (int m = 8; m < 64; m <<= 1)
        #pragma unroll
        for (int t = 0; t < 8; t++)
            acc[t] += __shfl_xor(acc[t], m);

    float inv = (deg > 0) ? 1.0f / (float)deg : 0.0f;
    float b[8], a[8];
    #pragma unroll
    for (int t = 0; t < 8; t++) b[t] = acc[t] * inv;

    uint4 ua = *(const uint4*)(x1_h + ((size_t)node << 6) + fid);
    unp8(ua, a);

    float dot = 0.f, nn1 = 0.f, nn2 = 0.f;
    #pragma unroll
    for (int t = 0; t < 8; t++) {
        dot += a[t] * b[t];
        nn1 += a[t] * a[t];
        nn2 += b[t] * b[t];
    }
    #pragma unroll
    for (int m = 1; m < 64; m <<= 1) {
        dot += __shfl_xor(dot, m);
        nn1 += __shfl_xor(nn1, m);
        nn2 += __shfl_xor(nn2, m);
    }
    dot *= 0.125f; nn1 *= 0.125f; nn2 *= 0.125f;  // 8 groups duplicate

    float w = dot / fmaxf(sqrtf(nn1) * sqrtf(nn2), 1e-8f);
    if (lane < 8) {
        float omw = 1.0f - w;
        float4 r0, r1;
        r0.x = w*b[0] + omw*a[0]; r0.y = w*b[1] + omw*a[1];
        r0.z = w*b[2] + omw*a[2]; r0.w = w*b[3] + omw*a[3];
        r1.x = w*b[4] + omw*a[4]; r1.y = w*b[5] + omw*a[5];
        r1.z = w*b[6] + omw*a[6]; r1.w = w*b[7] + omw*a[7];
        float* po = out + ((size_t)node << 6) + fid;
        *(float4*)po = r0;
        *(float4*)(po + 4) = r1;
    }
}

// ---- launch -------------------------------------------------------------

extern "C" void kernel_launch(void* const* d_in, const int* in_sizes, int n_in,
                              void* d_out, int out_size, void* d_ws, size_t ws_size,
                              hipStream_t stream) {
    const float* feat = (const float*)d_in[0];
    const int*   eidx = (const int*)d_in[1];
    const int4*  src4 = (const int4*)eidx;
    const int4*  dst4 = (const int4*)(eidx + N_EDGES);

    __half*       feat_h  = (__half*)d_ws;                          // 12.8 MB
    __half*       x1_h    = feat_h + (size_t)N_NODES * D_FEAT;      // 12.8 MB
    unsigned int* tmp1    = (unsigned int*)(x1_h + (size_t)N_NODES * D_FEAT); // 6.4 MB
    int*          csr_src = (int*)(tmp1 + N_EDGES);                 // 6.4 MB
    int*          offsets = csr_src + N_EDGES;                      // 100001
    int*          percnt  = offsets + (N_NODES + 1);                // NBC*F1_WGS
    int*          bhist   = percnt + NBC * F1_WGS;                  // NBC
    int*          bbase   = bhist + NBC;                            // NBC+1
    float*        out     = (float*)d_out;

    cast_and_hist <<<F1_WGS + CAST_BLOCKS, 256, 0, stream>>>(feat, feat_h, dst4, percnt);
    bucket_colscan<<<NBC, F1_WGS, 0, stream>>>(percnt, bhist);
    bucket_scan   <<<1, 256, 0, stream>>>(bhist, bbase);
    bucketize     <<<F1_WGS, 256, 0, stream>>>(src4, dst4, bbase, percnt, tmp1);
    bucket_csr    <<<NBC, NPB, 0, stream>>>(tmp1, bbase, offsets, csr_src);

    const int BLK = 256;
    int nblocks = (N_NODES + 3) / 4;
    gather1_kernel<<<nblocks, BLK, 0, stream>>>(feat_h, offsets, csr_src, x1_h);
    gather2_finalize_kernel<<<nblocks, BLK, 0, stream>>>(x1_h, offsets, csr_src, out);
}